// Round 4
// baseline (255.115 us; speedup 1.0000x reference)
//
#include <hip/hip_runtime.h>
#include <hip/hip_bf16.h>
#include <stdint.h>

typedef unsigned short u16;
typedef unsigned int   u32;
typedef uint64_t       u64;

using f32x4  = __attribute__((ext_vector_type(4))) float;
using bf16x8 = __attribute__((ext_vector_type(8))) short;

// ---------- helpers ----------
__device__ __forceinline__ u16 f2bf(float f){
  u32 x = __builtin_bit_cast(u32, f);
  x = x + 0x7fffu + ((x >> 16) & 1u);   // RNE
  return (u16)(x >> 16);
}

__device__ __forceinline__ void gload16(const void* g, void* l){
  __builtin_amdgcn_global_load_lds(
      (const __attribute__((address_space(1))) void*)g,
      (__attribute__((address_space(3))) void*)l, 16, 0, 0);
}

__device__ __forceinline__ bf16x8 mkfrag(uint2 h0, uint2 h1){
  union { bf16x8 v; u32 u[4]; } f;
  f.u[0]=h0.x; f.u[1]=h0.y; f.u[2]=h1.x; f.u[3]=h1.y;
  return f.v;
}

// ---------- small converters ----------
__global__ void convx(const float* __restrict__ in, u16* __restrict__ out, int n4){
  for (int i = blockIdx.x*256 + threadIdx.x; i < n4; i += gridDim.x*256){
    float4 v = ((const float4*)in)[i];
    ushort4 o;
    o.x = f2bf(v.x); o.y = f2bf(v.y); o.z = f2bf(v.z); o.w = f2bf(v.w);
    ((ushort4*)out)[i] = o;
  }
}

// in: K x N fp32 (row-major), out: N x K bf16 (transposed)
__global__ __launch_bounds__(256) void wtrans(const float* __restrict__ in,
                                              u16* __restrict__ out, int K, int N){
  __shared__ float tile[32][33];
  const int t = threadIdx.x;
  const int n0 = blockIdx.x*32, k0 = blockIdx.y*32;
  const int r = t >> 3, c4 = (t & 7)*4;
  const float4 v = *(const float4*)(in + (u64)(k0 + r)*N + n0 + c4);
  tile[r][c4+0]=v.x; tile[r][c4+1]=v.y; tile[r][c4+2]=v.z; tile[r][c4+3]=v.w;
  __syncthreads();
  ushort4 o;
  o.x = f2bf(tile[c4+0][r]); o.y = f2bf(tile[c4+1][r]);
  o.z = f2bf(tile[c4+2][r]); o.w = f2bf(tile[c4+3][r]);
  *(ushort4*)(out + (u64)(n0 + r)*K + k0 + c4) = o;
}

// ---------- temperature MLP ----------
__global__ __launch_bounds__(384) void temp_kernel(
    const float* __restrict__ x, const float* __restrict__ w1,
    const float* __restrict__ b1, const float* __restrict__ w2,
    const float* __restrict__ b2, float* __restrict__ lsc){
  const int b = blockIdx.x, t = threadIdx.x;
  __shared__ float cls[768];
  __shared__ float part[6];
  const float* xr = x + (u64)b*577*768;
  cls[t] = xr[t]; cls[t+384] = xr[t+384];
  __syncthreads();
  float h0 = 0.f, h1 = 0.f, h2 = 0.f, h3 = 0.f;
  for (int i = 0; i < 768; i += 4){
    h0 = fmaf(cls[i+0], w1[(u64)(i+0)*384 + t], h0);
    h1 = fmaf(cls[i+1], w1[(u64)(i+1)*384 + t], h1);
    h2 = fmaf(cls[i+2], w1[(u64)(i+2)*384 + t], h2);
    h3 = fmaf(cls[i+3], w1[(u64)(i+3)*384 + t], h3);
  }
  float hacc = fmaxf((h0 + h1) + (h2 + h3) + b1[t], 0.f);
  float v = hacc * w2[t];
  #pragma unroll
  for (int off = 1; off < 64; off <<= 1) v += __shfl_xor(v, off);
  if ((t & 63) == 0) part[t >> 6] = v;
  __syncthreads();
  if (t == 0){
    float s2 = b2[0];
    for (int i = 0; i < 6; i++) s2 += part[i];
    float sig  = 1.f / (1.f + expf(-s2));
    float temp = 0.5f + 2.5f * sig;          // TEMP_MIN + (MAX-MIN)*sigmoid
    lsc[b] = 0.125f / temp;                  // D^-0.5 / temperature
  }
}

// ---------- GEMM: A[M][768] x Bm[N][768]^T ----------
// OUTF=1 -> f32 out + bias; OUTF=2 -> bf16 out, cols<768 scaled by lsc[row/577]
// BK=64, LDS tiles [128][64] u16, 16B-unit XOR swizzle unit' = unit ^ (row&7),
// staged via global_load_lds (linear LDS dest) + pre-swizzled global source.
template<int OUTF>
__global__ __launch_bounds__(256, 2) void gemm_nt(
    const u16* __restrict__ A, const u16* __restrict__ Bm,
    void* __restrict__ Cout, const float* __restrict__ bias,
    const float* __restrict__ lsc, int M, int N){
  constexpr int K = 768;
  __shared__ u16 As[128*64];
  __shared__ u16 Bs[128*64];
  const int t = threadIdx.x, l = t & 63, w = t >> 6;
  const int bm = blockIdx.y*128, bn = blockIdx.x*128;
  const int wr = (w >> 1)*64, wc = (w & 1)*64;
  const int g = l >> 4, r16 = l & 15;

  f32x4 acc[4][4];
  #pragma unroll
  for (int i = 0; i < 4; i++)
    #pragma unroll
    for (int j = 0; j < 4; j++) acc[i][j] = (f32x4){0.f,0.f,0.f,0.f};

  const int srow = t >> 3;                  // 0..31
  const int su   = (t & 7) ^ (srow & 7);    // source 16B-unit within the 64-k slab
  const u16* gA[4]; const u16* gB[4];
  #pragma unroll
  for (int i = 0; i < 4; i++){
    int ra = bm + i*32 + srow; if (ra > M-1) ra = M-1;
    gA[i] = A  + (u64)ra*K + su*8;
    gB[i] = Bm + (u64)(bn + i*32 + srow)*K + su*8;
  }
  u16* lA = As + t*8;
  u16* lB = Bs + t*8;

  for (int kt = 0; kt < K; kt += 64){
    #pragma unroll
    for (int i = 0; i < 4; i++) gload16(gA[i] + kt, lA + i*2048);
    #pragma unroll
    for (int i = 0; i < 4; i++) gload16(gB[i] + kt, lB + i*2048);
    __syncthreads();
    #pragma unroll
    for (int s = 0; s < 2; s++){
      const int c   = s*4 + (g >> 1);
      const int off = (g & 1)*4;
      bf16x8 af[4], bfr[4];
      #pragma unroll
      for (int m = 0; m < 4; m++){
        const int R = wr + m*16 + r16;
        const int i1 = R*64 + ((c ^ (R & 7))*8) + off;
        af[m] = mkfrag(*(const uint2*)(As + i1), *(const uint2*)(As + (i1 ^ 16)));
      }
      #pragma unroll
      for (int n = 0; n < 4; n++){
        const int R = wc + n*16 + r16;
        const int i1 = R*64 + ((c ^ (R & 7))*8) + off;
        bfr[n] = mkfrag(*(const uint2*)(Bs + i1), *(const uint2*)(Bs + (i1 ^ 16)));
      }
      #pragma unroll
      for (int m = 0; m < 4; m++)
        #pragma unroll
        for (int n = 0; n < 4; n++)
          acc[m][n] = __builtin_amdgcn_mfma_f32_16x16x32_bf16(af[m], bfr[n], acc[m][n], 0, 0, 0);
    }
    __syncthreads();
  }
  const int row0 = bm + wr + g*4;
  const int col0 = bn + wc + r16;
  const bool isQ = (OUTF == 2) && (bn < 768);   // block-uniform
  #pragma unroll
  for (int m = 0; m < 4; m++){
    #pragma unroll
    for (int rr = 0; rr < 4; rr++){
      const int row = row0 + m*16 + rr;
      if (row < M){
        float qs = 1.0f;
        if (isQ) qs = lsc[row/577];
        #pragma unroll
        for (int n = 0; n < 4; n++){
          const int col = col0 + n*16;
          const float v = acc[m][n][rr];
          if (OUTF == 1) ((float*)Cout)[(u64)row*N + col] = v + bias[col];
          else           ((u16*)Cout)[(u64)row*N + col]  = f2bf(v*qs);
        }
      }
    }
  }
}

// ---------- flash attention ----------
// qkv: [9296][2304] bf16 (rows >= 9232 are pad; masked out). out: [B*577][768] bf16.
// Q pre-scaled by D^-0.5/temperature in the qkv GEMM.
// Double-buffered K/Vt LDS + async stage split: issue tile t+1 loads before
// computing tile t; V regs -> LDS after PV; ONE barrier per iteration.
__global__ __launch_bounds__(256, 2) void attn_kernel(
    const u16* __restrict__ qkv, u16* __restrict__ aout){
  const int qt = blockIdx.x, h = blockIdx.y, b = blockIdx.z;
  const int t = threadIdx.x, w = t >> 6, l = t & 63;
  const int g = l >> 4, r16 = l & 15;
  __shared__ u16 Ks[2][64*64];   // [key][d], 16B-unit XOR swizzle key=(row&7)
  __shared__ u16 Vt[2][64*64];   // [d][key], swizzle key=((d^(d>>3))&7)
  const u16* base = qkv + (u64)b*577*2304 + (u64)h*64;

  int qn = qt*64 + w*16 + r16; if (qn > 576) qn = 576;
  bf16x8 qf[2];
  {
    const u16* qr = base + (u64)qn*2304;
    #pragma unroll
    for (int s = 0; s < 2; s++)
      qf[s] = mkfrag(*(const uint2*)(qr + s*32 + g*4),
                     *(const uint2*)(qr + s*32 + g*4 + 16));
  }
  float m_run = -1e30f, l_run = 0.f;
  f32x4 oacc[4];
  #pragma unroll
  for (int i = 0; i < 4; i++) oacc[i] = (f32x4){0,0,0,0};

  const int srcb = (l & 48) | (((l >> 4) & 3)*4);   // lane holding q-row 4g+rr at +rr

  // staging sources (point at NEXT tile to load)
  const int srow = t >> 3;                         // 0..31
  const int su   = (t & 7) ^ (srow & 7);           // pre-swizzled K source unit
  const u16* pK = base + 768  + (u64)srow*2304 + su*8;
  const int kr0 = (t >> 3)*2;                      // V: two consecutive key rows
  const u16* pV = base + 1536 + (u64)kr0*2304 + (t & 7)*8;
  // kt-invariant Vt scatter offsets (u16 units)
  u32 vtoff[8];
  #pragma unroll
  for (int j = 0; j < 8; j++){
    const int d = (t & 7)*8 + j;
    const int key = (d ^ (d >> 3)) & 7;
    vtoff[j] = d*64 + (((kr0 >> 3) ^ key)*8) + (kr0 & 7);
  }

  uint4 vr0, vr1;
  // ---- prologue: stage tile 0 ----
  gload16(pK,            &Ks[0][0] + t*8);
  gload16(pK + 32*2304,  &Ks[0][0] + t*8 + 2048);
  vr0 = *(const uint4*)pV;
  vr1 = *(const uint4*)(pV + 2304);
  pK += 64*2304; pV += 64*2304;
  {
    const u16* e0 = (const u16*)&vr0;
    const u16* e1 = (const u16*)&vr1;
    #pragma unroll
    for (int j = 0; j < 8; j++)
      *(u32*)(&Vt[0][0] + vtoff[j]) = (u32)e0[j] | ((u32)e1[j] << 16);
  }
  __syncthreads();

  for (int kt = 0; kt < 10; kt++){
    const int cur = kt & 1, nb = cur ^ 1;
    u16* ksc = &Ks[cur][0];
    u16* vtc = &Vt[cur][0];
    // issue next-tile loads (hidden under this tile's compute)
    if (kt < 9){
      gload16(pK,           &Ks[nb][0] + t*8);
      gload16(pK + 32*2304, &Ks[nb][0] + t*8 + 2048);
      vr0 = *(const uint4*)pV;
      vr1 = *(const uint4*)(pV + 2304);
      pK += 64*2304; pV += 64*2304;
    }

    // S^T = K Q^T  (lane holds keys fn*16+4g+rr for q-row r16)
    f32x4 sacc[4];
    #pragma unroll
    for (int i = 0; i < 4; i++) sacc[i] = (f32x4){0,0,0,0};
    #pragma unroll
    for (int fn = 0; fn < 4; fn++){
      const int kr = fn*16 + r16;
      const int kk = kr & 7;
      const u16* rowp = ksc + kr*64 + (g & 1)*4;
      #pragma unroll
      for (int s = 0; s < 2; s++){
        const int b0 = (4*s + (g >> 1)) ^ kk;
        sacc[fn] = __builtin_amdgcn_mfma_f32_16x16x32_bf16(
            mkfrag(*(const uint2*)(rowp + b0*8), *(const uint2*)(rowp + (b0 ^ 2)*8)),
            qf[s], sacc[fn], 0, 0, 0);
      }
    }
    // mask (only the last tile has keys > 576)
    if (kt == 9){
      #pragma unroll
      for (int fn = 0; fn < 4; fn++)
        #pragma unroll
        for (int rr = 0; rr < 4; rr++){
          const bool valid = (576 + fn*16 + g*4 + rr) <= 576;
          sacc[fn][rr] = valid ? sacc[fn][rr] : -1e30f;
        }
    }
    // online softmax: all 16 values on a lane belong to q-row r16
    float mx = sacc[0][0];
    #pragma unroll
    for (int fn = 0; fn < 4; fn++)
      #pragma unroll
      for (int rr = 0; rr < 4; rr++) mx = fmaxf(mx, sacc[fn][rr]);
    mx = fmaxf(mx, __shfl_xor(mx, 16));
    mx = fmaxf(mx, __shfl_xor(mx, 32));
    const float nm = fmaxf(m_run, mx);
    const float corr = __expf(m_run - nm);
    m_run = nm;
    float rs = 0.f;
    u16 pb[4][4];
    #pragma unroll
    for (int fn = 0; fn < 4; fn++)
      #pragma unroll
      for (int rr = 0; rr < 4; rr++){
        const float p = __expf(sacc[fn][rr] - m_run);
        rs += p;
        pb[fn][rr] = f2bf(p);
      }
    rs += __shfl_xor(rs, 16);
    rs += __shfl_xor(rs, 32);
    l_run = l_run*corr + rs;
    // rescale O rows (lane's O rows are q = 4g+rr -> broadcast corr)
    float corrO[4];
    #pragma unroll
    for (int rr = 0; rr < 4; rr++) corrO[rr] = __shfl(corr, srcb + rr);
    #pragma unroll
    for (int df = 0; df < 4; df++)
      #pragma unroll
      for (int rr = 0; rr < 4; rr++)
        oacc[df][rr] *= corrO[rr];
    // O += P V  (P fragments straight from registers)
    #pragma unroll
    for (int s = 0; s < 2; s++){
      union { bf16x8 v; u32 u[4]; } pa;
      pa.u[0] = (u32)pb[2*s][0]   | ((u32)pb[2*s][1]   << 16);
      pa.u[1] = (u32)pb[2*s][2]   | ((u32)pb[2*s][3]   << 16);
      pa.u[2] = (u32)pb[2*s+1][0] | ((u32)pb[2*s+1][1] << 16);
      pa.u[3] = (u32)pb[2*s+1][2] | ((u32)pb[2*s+1][3] << 16);
      #pragma unroll
      for (int df = 0; df < 4; df++){
        const int vd = df*16 + r16;
        const int vk = (vd ^ (vd >> 3)) & 7;
        const u16* vrp = vtc + vd*64 + (g & 1)*4;
        const int c0 = (4*s + (g >> 1)) ^ vk;
        const bf16x8 vf = mkfrag(*(const uint2*)(vrp + c0*8),
                                 *(const uint2*)(vrp + (c0 ^ 2)*8));
        oacc[df] = __builtin_amdgcn_mfma_f32_16x16x32_bf16(pa.v, vf, oacc[df], 0, 0, 0);
      }
    }
    // commit next V tile to LDS (waits the vr loads; barrier drains gload_lds)
    if (kt < 9){
      const u16* e0 = (const u16*)&vr0;
      const u16* e1 = (const u16*)&vr1;
      u16* vtn = &Vt[nb][0];
      #pragma unroll
      for (int j = 0; j < 8; j++)
        *(u32*)(vtn + vtoff[j]) = (u32)e0[j] | ((u32)e1[j] << 16);
    }
    __syncthreads();
  }
  // epilogue: O/l -> bf16 [row][h*64+d]
  float lO[4];
  #pragma unroll
  for (int rr = 0; rr < 4; rr++) lO[rr] = __shfl(l_run, srcb + rr);
  #pragma unroll
  for (int df = 0; df < 4; df++){
    const int d = df*16 + r16;
    #pragma unroll
    for (int rr = 0; rr < 4; rr++){
      const int n = qt*64 + w*16 + g*4 + rr;
      if (n <= 576){
        const float v = oacc[df][rr] / lO[rr];
        aout[(u64)(b*577 + n)*768 + h*64 + d] = f2bf(v);
      }
    }
  }
}

// ---------- launcher ----------
extern "C" void kernel_launch(void* const* d_in, const int* in_sizes, int n_in,
                              void* d_out, int out_size, void* d_ws, size_t ws_size,
                              hipStream_t stream){
  const float* x      = (const float*)d_in[0];
  const float* qkv_w  = (const float*)d_in[1];
  const float* proj_w = (const float*)d_in[2];
  const float* proj_b = (const float*)d_in[3];
  const float* t_w1   = (const float*)d_in[4];
  const float* t_b1   = (const float*)d_in[5];
  const float* t_w2   = (const float*)d_in[6];
  const float* t_b2   = (const float*)d_in[7];

  // ws layout (256B-aligned). ao reuses xb's region (xb dead after qkv GEMM).
  // qkv padded to 9296 rows so attention staging needs no bounds clamps
  // (pad rows are 0xAA-poisoned => tiny bf16 values, masked in softmax).
  const u64 off_xb  = 256;                    // x bf16 [9232][768]  / later: attn out
  const u64 off_qwT = off_xb  + 14180352ull;  // qkv_w^T [2304][768]
  const u64 off_pwT = off_qwT + 3538944ull;   // proj_w^T [768][768]
  const u64 off_qkv = off_pwT + 1179648ull;   // qkv bf16 [9296][2304]
  const u64 need    = off_qkv + 42835968ull;
  if (ws_size < need) return;  // visible-failure guard: output stays poisoned

  char* ws  = (char*)d_ws;
  float* lsc = (float*)ws;
  u16* xb   = (u16*)(ws + off_xb);
  u16* qwT  = (u16*)(ws + off_qwT);
  u16* pwT  = (u16*)(ws + off_pwT);
  u16* qkv  = (u16*)(ws + off_qkv);
  u16* ao   = xb;   // reuse

  convx<<<1024, 256, 0, stream>>>(x, xb, (16*577*768)/4);
  wtrans<<<dim3(2304/32, 768/32), 256, 0, stream>>>(qkv_w, qwT, 768, 2304);
  wtrans<<<dim3(768/32, 768/32), 256, 0, stream>>>(proj_w, pwT, 768, 768);
  temp_kernel<<<16, 384, 0, stream>>>(x, t_w1, t_b1, t_w2, t_b2, lsc);
  gemm_nt<2><<<dim3(2304/128, 73), 256, 0, stream>>>(xb, qwT, qkv, nullptr, lsc, 9232, 2304);
  attn_kernel<<<dim3(10, 12, 16), 256, 0, stream>>>(qkv, ao);
  gemm_nt<1><<<dim3(768/128, 73), 256, 0, stream>>>(ao, pwT, d_out, proj_b, nullptr, 9232, 768);
}

// Round 5
// 238.276 us; speedup vs baseline: 1.0707x; 1.0707x over previous
//
#include <hip/hip_runtime.h>
#include <hip/hip_bf16.h>
#include <stdint.h>

typedef unsigned short u16;
typedef unsigned int   u32;
typedef uint64_t       u64;

using f32x4  = __attribute__((ext_vector_type(4))) float;
using bf16x8 = __attribute__((ext_vector_type(8))) short;

// ---------- helpers ----------
__device__ __forceinline__ u16 f2bf(float f){
  u32 x = __builtin_bit_cast(u32, f);
  x = x + 0x7fffu + ((x >> 16) & 1u);   // RNE
  return (u16)(x >> 16);
}

__device__ __forceinline__ void gload16(const void* g, void* l){
  __builtin_amdgcn_global_load_lds(
      (const __attribute__((address_space(1))) void*)g,
      (__attribute__((address_space(3))) void*)l, 16, 0, 0);
}

__device__ __forceinline__ bf16x8 mkfrag(uint2 h0, uint2 h1){
  union { bf16x8 v; u32 u[4]; } f;
  f.u[0]=h0.x; f.u[1]=h0.y; f.u[2]=h1.x; f.u[3]=h1.y;
  return f.v;
}

// ---------- small converters ----------
__global__ void convx(const float* __restrict__ in, u16* __restrict__ out, int n4){
  for (int i = blockIdx.x*256 + threadIdx.x; i < n4; i += gridDim.x*256){
    float4 v = ((const float4*)in)[i];
    ushort4 o;
    o.x = f2bf(v.x); o.y = f2bf(v.y); o.z = f2bf(v.z); o.w = f2bf(v.w);
    ((ushort4*)out)[i] = o;
  }
}

// in: K x N fp32 (row-major), out: N x K bf16 (transposed)
__global__ __launch_bounds__(256) void wtrans(const float* __restrict__ in,
                                              u16* __restrict__ out, int K, int N){
  __shared__ float tile[32][33];
  const int t = threadIdx.x;
  const int n0 = blockIdx.x*32, k0 = blockIdx.y*32;
  const int r = t >> 3, c4 = (t & 7)*4;
  const float4 v = *(const float4*)(in + (u64)(k0 + r)*N + n0 + c4);
  tile[r][c4+0]=v.x; tile[r][c4+1]=v.y; tile[r][c4+2]=v.z; tile[r][c4+3]=v.w;
  __syncthreads();
  ushort4 o;
  o.x = f2bf(tile[c4+0][r]); o.y = f2bf(tile[c4+1][r]);
  o.z = f2bf(tile[c4+2][r]); o.w = f2bf(tile[c4+3][r]);
  *(ushort4*)(out + (u64)(n0 + r)*K + k0 + c4) = o;
}

// ---------- temperature MLP ----------
__global__ __launch_bounds__(384) void temp_kernel(
    const float* __restrict__ x, const float* __restrict__ w1,
    const float* __restrict__ b1, const float* __restrict__ w2,
    const float* __restrict__ b2, float* __restrict__ lsc){
  const int b = blockIdx.x, t = threadIdx.x;
  __shared__ float cls[768];
  __shared__ float part[6];
  const float* xr = x + (u64)b*577*768;
  cls[t] = xr[t]; cls[t+384] = xr[t+384];
  __syncthreads();
  float h0 = 0.f, h1 = 0.f, h2 = 0.f, h3 = 0.f;
  for (int i = 0; i < 768; i += 4){
    h0 = fmaf(cls[i+0], w1[(u64)(i+0)*384 + t], h0);
    h1 = fmaf(cls[i+1], w1[(u64)(i+1)*384 + t], h1);
    h2 = fmaf(cls[i+2], w1[(u64)(i+2)*384 + t], h2);
    h3 = fmaf(cls[i+3], w1[(u64)(i+3)*384 + t], h3);
  }
  float hacc = fmaxf((h0 + h1) + (h2 + h3) + b1[t], 0.f);
  float v = hacc * w2[t];
  #pragma unroll
  for (int off = 1; off < 64; off <<= 1) v += __shfl_xor(v, off);
  if ((t & 63) == 0) part[t >> 6] = v;
  __syncthreads();
  if (t == 0){
    float s2 = b2[0];
    for (int i = 0; i < 6; i++) s2 += part[i];
    float sig  = 1.f / (1.f + expf(-s2));
    float temp = 0.5f + 2.5f * sig;          // TEMP_MIN + (MAX-MIN)*sigmoid
    lsc[b] = 0.125f / temp;                  // D^-0.5 / temperature
  }
}

// ---------- GEMM: A[M][768] x Bm[N][768]^T ----------
// OUTF=1 -> f32 out + bias; OUTF=2 -> bf16 out, cols<768 scaled by lsc[row/577]
// BK=64, LDS tiles [128][64] u16, 16B-unit XOR swizzle unit' = unit ^ (row&7),
// staged via global_load_lds (linear LDS dest) + pre-swizzled global source.
template<int OUTF>
__global__ __launch_bounds__(256, 2) void gemm_nt(
    const u16* __restrict__ A, const u16* __restrict__ Bm,
    void* __restrict__ Cout, const float* __restrict__ bias,
    const float* __restrict__ lsc, int M, int N){
  constexpr int K = 768;
  __shared__ u16 As[128*64];
  __shared__ u16 Bs[128*64];
  const int t = threadIdx.x, l = t & 63, w = t >> 6;
  const int bm = blockIdx.y*128, bn = blockIdx.x*128;
  const int wr = (w >> 1)*64, wc = (w & 1)*64;
  const int g = l >> 4, r16 = l & 15;

  f32x4 acc[4][4];
  #pragma unroll
  for (int i = 0; i < 4; i++)
    #pragma unroll
    for (int j = 0; j < 4; j++) acc[i][j] = (f32x4){0.f,0.f,0.f,0.f};

  const int srow = t >> 3;                  // 0..31
  const int su   = (t & 7) ^ (srow & 7);    // source 16B-unit within the 64-k slab
  const u16* gA[4]; const u16* gB[4];
  #pragma unroll
  for (int i = 0; i < 4; i++){
    int ra = bm + i*32 + srow; if (ra > M-1) ra = M-1;
    gA[i] = A  + (u64)ra*K + su*8;
    gB[i] = Bm + (u64)(bn + i*32 + srow)*K + su*8;
  }
  u16* lA = As + t*8;
  u16* lB = Bs + t*8;

  for (int kt = 0; kt < K; kt += 64){
    #pragma unroll
    for (int i = 0; i < 4; i++) gload16(gA[i] + kt, lA + i*2048);
    #pragma unroll
    for (int i = 0; i < 4; i++) gload16(gB[i] + kt, lB + i*2048);
    __syncthreads();
    #pragma unroll
    for (int s = 0; s < 2; s++){
      const int c   = s*4 + (g >> 1);
      const int off = (g & 1)*4;
      bf16x8 af[4], bfr[4];
      #pragma unroll
      for (int m = 0; m < 4; m++){
        const int R = wr + m*16 + r16;
        const int i1 = R*64 + ((c ^ (R & 7))*8) + off;
        af[m] = mkfrag(*(const uint2*)(As + i1), *(const uint2*)(As + (i1 ^ 16)));
      }
      #pragma unroll
      for (int n = 0; n < 4; n++){
        const int R = wc + n*16 + r16;
        const int i1 = R*64 + ((c ^ (R & 7))*8) + off;
        bfr[n] = mkfrag(*(const uint2*)(Bs + i1), *(const uint2*)(Bs + (i1 ^ 16)));
      }
      #pragma unroll
      for (int m = 0; m < 4; m++)
        #pragma unroll
        for (int n = 0; n < 4; n++)
          acc[m][n] = __builtin_amdgcn_mfma_f32_16x16x32_bf16(af[m], bfr[n], acc[m][n], 0, 0, 0);
    }
    __syncthreads();
  }
  const int row0 = bm + wr + g*4;
  const int col0 = bn + wc + r16;
  const bool isQ = (OUTF == 2) && (bn < 768);   // block-uniform
  #pragma unroll
  for (int m = 0; m < 4; m++){
    #pragma unroll
    for (int rr = 0; rr < 4; rr++){
      const int row = row0 + m*16 + rr;
      if (row < M){
        float qs = 1.0f;
        if (isQ) qs = lsc[row/577];
        #pragma unroll
        for (int n = 0; n < 4; n++){
          const int col = col0 + n*16;
          const float v = acc[m][n][rr];
          if (OUTF == 1) ((float*)Cout)[(u64)row*N + col] = v + bias[col];
          else           ((u16*)Cout)[(u64)row*N + col]  = f2bf(v*qs);
        }
      }
    }
  }
}

// ---------- flash attention ----------
// qkv: [9232][2304] bf16 (q|k|v each H*64), Q pre-scaled by D^-0.5/temp.
// Main loop: 9 full K-tiles of 64 (no masking); key 576 handled by an
// in-register tail (dot + rank-1 update). Double-buffered K/Vt LDS, async
// stage split, ONE barrier per iteration. Register-resident P via S^T trick.
// VALU diet: cvt_pk_bf16_f32 packed P (T12), defer-max rescale THR=8 (T13).
// Grid: 1D 1920 with XCD-chunk swizzle so the 10 q-blocks sharing one
// (b,h)'s K/V land on the same XCD's L2 (T1).
__global__ __launch_bounds__(256, 2) void attn_kernel(
    const u16* __restrict__ qkv, u16* __restrict__ aout){
  const u32 lid  = blockIdx.x;
  const u32 orig = (lid & 7u)*240u + (lid >> 3);   // bijective: 1920 = 8*240
  const int qt = orig % 10u;
  const u32 bh = orig / 10u;
  const int h  = bh % 12u;
  const int b  = bh / 12u;
  const int t = threadIdx.x, w = t >> 6, l = t & 63;
  const int g = l >> 4, r16 = l & 15;
  __shared__ u16 Ks[2][64*64];   // [key][d], 16B-unit XOR swizzle key=(row&7)
  __shared__ u16 Vt[2][64*64];   // [d][key], swizzle key=((d^(d>>3))&7)
  const u16* base = qkv + (u64)b*577*2304 + (u64)h*64;

  int qn = qt*64 + w*16 + r16; if (qn > 576) qn = 576;
  bf16x8 qf[2];
  {
    const u16* qr = base + (u64)qn*2304;
    #pragma unroll
    for (int s = 0; s < 2; s++)
      qf[s] = mkfrag(*(const uint2*)(qr + s*32 + g*4),
                     *(const uint2*)(qr + s*32 + g*4 + 16));
  }
  float m_run = -1e30f, l_run = 0.f;
  f32x4 oacc[4];
  #pragma unroll
  for (int i = 0; i < 4; i++) oacc[i] = (f32x4){0,0,0,0};

  const int srcb = (l & 48) | (((l >> 4) & 3)*4);   // lane holding q-row 4g+rr at +rr

  // staging sources (point at NEXT tile to load)
  const int srow = t >> 3;                         // 0..31
  const int su   = (t & 7) ^ (srow & 7);           // pre-swizzled K source unit
  const u16* pK = base + 768  + (u64)srow*2304 + su*8;
  const int kr0 = (t >> 3)*2;                      // V: two consecutive key rows
  const u16* pV = base + 1536 + (u64)kr0*2304 + (t & 7)*8;
  // kt-invariant Vt scatter offsets (u16 units)
  u32 vtoff[8];
  #pragma unroll
  for (int j = 0; j < 8; j++){
    const int d = (t & 7)*8 + j;
    const int key = (d ^ (d >> 3)) & 7;
    vtoff[j] = d*64 + (((kr0 >> 3) ^ key)*8) + (kr0 & 7);
  }

  uint4 vr0, vr1;
  // ---- prologue: stage tile 0 ----
  gload16(pK,            &Ks[0][0] + t*8);
  gload16(pK + 32*2304,  &Ks[0][0] + t*8 + 2048);
  vr0 = *(const uint4*)pV;
  vr1 = *(const uint4*)(pV + 2304);
  pK += 64*2304; pV += 64*2304;
  {
    const u16* e0 = (const u16*)&vr0;
    const u16* e1 = (const u16*)&vr1;
    #pragma unroll
    for (int j = 0; j < 8; j++)
      *(u32*)(&Vt[0][0] + vtoff[j]) = (u32)e0[j] | ((u32)e1[j] << 16);
  }
  __syncthreads();

  for (int kt = 0; kt < 9; kt++){
    const int cur = kt & 1, nb = cur ^ 1;
    u16* ksc = &Ks[cur][0];
    u16* vtc = &Vt[cur][0];
    // issue next-tile loads (hidden under this tile's compute)
    if (kt < 8){
      gload16(pK,           &Ks[nb][0] + t*8);
      gload16(pK + 32*2304, &Ks[nb][0] + t*8 + 2048);
      vr0 = *(const uint4*)pV;
      vr1 = *(const uint4*)(pV + 2304);
      pK += 64*2304; pV += 64*2304;
    }

    // S^T = K Q^T  (lane holds keys fn*16+4g+rr for q-row r16)
    f32x4 sacc[4];
    #pragma unroll
    for (int i = 0; i < 4; i++) sacc[i] = (f32x4){0,0,0,0};
    #pragma unroll
    for (int fn = 0; fn < 4; fn++){
      const int kr = fn*16 + r16;
      const int kk = kr & 7;
      const u16* rowp = ksc + kr*64 + (g & 1)*4;
      #pragma unroll
      for (int s = 0; s < 2; s++){
        const int b0 = (4*s + (g >> 1)) ^ kk;
        sacc[fn] = __builtin_amdgcn_mfma_f32_16x16x32_bf16(
            mkfrag(*(const uint2*)(rowp + b0*8), *(const uint2*)(rowp + (b0 ^ 2)*8)),
            qf[s], sacc[fn], 0, 0, 0);
      }
    }
    // online softmax: all 16 values on a lane belong to q-row r16
    float mx = sacc[0][0];
    #pragma unroll
    for (int fn = 0; fn < 4; fn++)
      #pragma unroll
      for (int rr = 0; rr < 4; rr++) mx = fmaxf(mx, sacc[fn][rr]);
    mx = fmaxf(mx, __shfl_xor(mx, 16));
    mx = fmaxf(mx, __shfl_xor(mx, 32));
    // defer-max (T13): only rescale when the running max grew by > 8
    if (!__all(mx - m_run <= 8.f)){
      const float nm = fmaxf(m_run, mx);
      const float corr = __expf(m_run - nm);
      l_run *= corr;
      float corrO[4];
      #pragma unroll
      for (int rr = 0; rr < 4; rr++) corrO[rr] = __shfl(corr, srcb + rr);
      #pragma unroll
      for (int df = 0; df < 4; df++)
        #pragma unroll
        for (int rr = 0; rr < 4; rr++) oacc[df][rr] *= corrO[rr];
      m_run = nm;
    }
    float pf[4][4];
    float rs = 0.f;
    #pragma unroll
    for (int fn = 0; fn < 4; fn++)
      #pragma unroll
      for (int rr = 0; rr < 4; rr++){
        const float p = __expf(sacc[fn][rr] - m_run);   // bounded by e^8
        rs += p;
        pf[fn][rr] = p;
      }
    rs += __shfl_xor(rs, 16);
    rs += __shfl_xor(rs, 32);
    l_run += rs;
    // O += P V  (P packed in-register via v_cvt_pk_bf16_f32, T12)
    #pragma unroll
    for (int s = 0; s < 2; s++){
      union { bf16x8 v; u32 u[4]; } pa;
      asm("v_cvt_pk_bf16_f32 %0, %1, %2" : "=v"(pa.u[0]) : "v"(pf[2*s][0]),   "v"(pf[2*s][1]));
      asm("v_cvt_pk_bf16_f32 %0, %1, %2" : "=v"(pa.u[1]) : "v"(pf[2*s][2]),   "v"(pf[2*s][3]));
      asm("v_cvt_pk_bf16_f32 %0, %1, %2" : "=v"(pa.u[2]) : "v"(pf[2*s+1][0]), "v"(pf[2*s+1][1]));
      asm("v_cvt_pk_bf16_f32 %0, %1, %2" : "=v"(pa.u[3]) : "v"(pf[2*s+1][2]), "v"(pf[2*s+1][3]));
      #pragma unroll
      for (int df = 0; df < 4; df++){
        const int vd = df*16 + r16;
        const int vk = (vd ^ (vd >> 3)) & 7;
        const u16* vrp = vtc + vd*64 + (g & 1)*4;
        const int c0 = (4*s + (g >> 1)) ^ vk;
        const bf16x8 vf = mkfrag(*(const uint2*)(vrp + c0*8),
                                 *(const uint2*)(vrp + (c0 ^ 2)*8));
        oacc[df] = __builtin_amdgcn_mfma_f32_16x16x32_bf16(pa.v, vf, oacc[df], 0, 0, 0);
      }
    }
    // commit next V tile to LDS, then barrier (drains gload_lds too)
    if (kt < 8){
      const u16* e0 = (const u16*)&vr0;
      const u16* e1 = (const u16*)&vr1;
      u16* vtn = &Vt[nb][0];
      #pragma unroll
      for (int j = 0; j < 8; j++)
        *(u32*)(vtn + vtoff[j]) = (u32)e0[j] | ((u32)e1[j] << 16);
      __syncthreads();
    }
  }

  // ---- tail: key 576 (in-register dot + rank-1 update) ----
  {
    const u16* kr576 = base + 768 + (u64)576*2304;
    float s576 = 0.f;
    #pragma unroll
    for (int s = 0; s < 2; s++){
      const uint2 k0 = *(const uint2*)(kr576 + s*32 + g*4);
      const uint2 k1 = *(const uint2*)(kr576 + s*32 + g*4 + 16);
      union { bf16x8 v; u32 u[4]; } qq; qq.v = qf[s];
      const u32 ku[4] = {k0.x, k0.y, k1.x, k1.y};
      #pragma unroll
      for (int j = 0; j < 4; j++){
        const float ql = __builtin_bit_cast(float, qq.u[j] << 16);
        const float qh = __builtin_bit_cast(float, qq.u[j] & 0xffff0000u);
        const float kl = __builtin_bit_cast(float, ku[j] << 16);
        const float kh = __builtin_bit_cast(float, ku[j] & 0xffff0000u);
        s576 = fmaf(ql, kl, s576);
        s576 = fmaf(qh, kh, s576);
      }
    }
    s576 += __shfl_xor(s576, 16);
    s576 += __shfl_xor(s576, 32);
    if (!__all(s576 - m_run <= 8.f)){
      const float nm = fmaxf(m_run, s576);
      const float corr = __expf(m_run - nm);
      l_run *= corr;
      float corrO[4];
      #pragma unroll
      for (int rr = 0; rr < 4; rr++) corrO[rr] = __shfl(corr, srcb + rr);
      #pragma unroll
      for (int df = 0; df < 4; df++)
        #pragma unroll
        for (int rr = 0; rr < 4; rr++) oacc[df][rr] *= corrO[rr];
      m_run = nm;
    }
    const float p576 = __expf(s576 - m_run);
    l_run += p576;
    float pbr[4];
    #pragma unroll
    for (int rr = 0; rr < 4; rr++) pbr[rr] = __shfl(p576, srcb + rr);
    const u16* v576 = base + 1536 + (u64)576*2304;
    #pragma unroll
    for (int df = 0; df < 4; df++){
      const float vv = __builtin_bit_cast(float, (u32)v576[df*16 + r16] << 16);
      #pragma unroll
      for (int rr = 0; rr < 4; rr++)
        oacc[df][rr] = fmaf(pbr[rr], vv, oacc[df][rr]);
    }
  }

  // epilogue: O/l -> bf16 [row][h*64+d]
  float lO[4];
  #pragma unroll
  for (int rr = 0; rr < 4; rr++) lO[rr] = __shfl(l_run, srcb + rr);
  #pragma unroll
  for (int df = 0; df < 4; df++){
    const int d = df*16 + r16;
    #pragma unroll
    for (int rr = 0; rr < 4; rr++){
      const int n = qt*64 + w*16 + g*4 + rr;
      if (n <= 576){
        const float v = oacc[df][rr] / lO[rr];
        aout[(u64)(b*577 + n)*768 + h*64 + d] = f2bf(v);
      }
    }
  }
}

// ---------- launcher ----------
extern "C" void kernel_launch(void* const* d_in, const int* in_sizes, int n_in,
                              void* d_out, int out_size, void* d_ws, size_t ws_size,
                              hipStream_t stream){
  const float* x      = (const float*)d_in[0];
  const float* qkv_w  = (const float*)d_in[1];
  const float* proj_w = (const float*)d_in[2];
  const float* proj_b = (const float*)d_in[3];
  const float* t_w1   = (const float*)d_in[4];
  const float* t_b1   = (const float*)d_in[5];
  const float* t_w2   = (const float*)d_in[6];
  const float* t_b2   = (const float*)d_in[7];

  // ws layout (256B-aligned). ao reuses xb's region (xb dead after qkv GEMM).
  const u64 off_xb  = 256;                    // x bf16 [9232][768]  / later: attn out
  const u64 off_qwT = off_xb  + 14180352ull;  // qkv_w^T [2304][768]
  const u64 off_pwT = off_qwT + 3538944ull;   // proj_w^T [768][768]
  const u64 off_qkv = off_pwT + 1179648ull;   // qkv bf16 [9232][2304]
  const u64 need    = off_qkv + 42541056ull;
  if (ws_size < need) return;  // visible-failure guard: output stays poisoned

  char* ws  = (char*)d_ws;
  float* lsc = (float*)ws;
  u16* xb   = (u16*)(ws + off_xb);
  u16* qwT  = (u16*)(ws + off_qwT);
  u16* pwT  = (u16*)(ws + off_pwT);
  u16* qkv  = (u16*)(ws + off_qkv);
  u16* ao   = xb;   // reuse

  convx<<<1024, 256, 0, stream>>>(x, xb, (16*577*768)/4);
  wtrans<<<dim3(2304/32, 768/32), 256, 0, stream>>>(qkv_w, qwT, 768, 2304);
  wtrans<<<dim3(768/32, 768/32), 256, 0, stream>>>(proj_w, pwT, 768, 768);
  temp_kernel<<<16, 384, 0, stream>>>(x, t_w1, t_b1, t_w2, t_b2, lsc);
  gemm_nt<2><<<dim3(2304/128, 73), 256, 0, stream>>>(xb, qwT, qkv, nullptr, lsc, 9232, 2304);
  attn_kernel<<<1920, 256, 0, stream>>>(qkv, ao);
  gemm_nt<1><<<dim3(768/128, 73), 256, 0, stream>>>(ao, pwT, d_out, proj_b, nullptr, 9232, 768);
}

// Round 8
// 232.927 us; speedup vs baseline: 1.0953x; 1.0230x over previous
//
#include <hip/hip_runtime.h>
#include <hip/hip_bf16.h>
#include <stdint.h>

typedef unsigned short u16;
typedef unsigned int   u32;
typedef uint64_t       u64;

using f32x4  = __attribute__((ext_vector_type(4))) float;
using bf16x8 = __attribute__((ext_vector_type(8))) short;

// ---------- helpers ----------
__device__ __forceinline__ u16 f2bf(float f){
  u32 x = __builtin_bit_cast(u32, f);
  x = x + 0x7fffu + ((x >> 16) & 1u);   // RNE
  return (u16)(x >> 16);
}

__device__ __forceinline__ void gload16(const void* g, void* l){
  __builtin_amdgcn_global_load_lds(
      (const __attribute__((address_space(1))) void*)g,
      (__attribute__((address_space(3))) void*)l, 16, 0, 0);
}

__device__ __forceinline__ bf16x8 mkfrag(uint2 h0, uint2 h1){
  union { bf16x8 v; u32 u[4]; } f;
  f.u[0]=h0.x; f.u[1]=h0.y; f.u[2]=h1.x; f.u[3]=h1.y;
  return f.v;
}

// ---------- fused prep: convx | wtrans(qkv_w) | wtrans(proj_w) | temperature ----------
// grid layout: [0,1024) convx, [1024,2752) wtrans qkv_w (72x24),
//              [2752,3328) wtrans proj_w (24x24), [3328,3344) temp (16 blocks)
__global__ __launch_bounds__(256) void prep_kernel(
    const float* __restrict__ x, const float* __restrict__ qkv_w,
    const float* __restrict__ proj_w,
    const float* __restrict__ t_w1, const float* __restrict__ t_b1,
    const float* __restrict__ t_w2, const float* __restrict__ t_b2,
    u16* __restrict__ xb, u16* __restrict__ qwT, u16* __restrict__ pwT,
    float* __restrict__ lsc){
  __shared__ float tile[32][33];
  __shared__ float cls[768];
  __shared__ float part[4];
  const int bid = blockIdx.x, t = threadIdx.x;

  if (bid < 1024){
    // ---- x -> bf16 ----
    const int n4 = 16*577*768/4;
    for (int i = bid*256 + t; i < n4; i += 1024*256){
      float4 v = ((const float4*)x)[i];
      ushort4 o;
      o.x = f2bf(v.x); o.y = f2bf(v.y); o.z = f2bf(v.z); o.w = f2bf(v.w);
      ((ushort4*)xb)[i] = o;
    }
  } else if (bid < 3328){
    // ---- weight transpose (K x N f32 -> N x K bf16) ----
    const bool isQ = bid < 2752;
    const int r    = isQ ? (bid - 1024) : (bid - 2752);
    const int nbx  = isQ ? 72 : 24;
    const int N    = isQ ? 2304 : 768;
    const float* in = isQ ? qkv_w : proj_w;
    u16* out        = isQ ? qwT   : pwT;
    const int n0 = (r % nbx)*32, k0 = (r / nbx)*32;
    const int rr = t >> 3, c4 = (t & 7)*4;
    const float4 v = *(const float4*)(in + (u64)(k0 + rr)*N + n0 + c4);
    tile[rr][c4+0]=v.x; tile[rr][c4+1]=v.y; tile[rr][c4+2]=v.z; tile[rr][c4+3]=v.w;
    __syncthreads();
    ushort4 o;
    o.x = f2bf(tile[c4+0][rr]); o.y = f2bf(tile[c4+1][rr]);
    o.z = f2bf(tile[c4+2][rr]); o.w = f2bf(tile[c4+3][rr]);
    *(ushort4*)(out + (u64)(n0 + rr)*768 + k0 + c4) = o;
  } else {
    // ---- temperature MLP for batch b ----
    const int b = bid - 3328;
    const float* xr = x + (u64)b*577*768;
    cls[t] = xr[t]; cls[t+256] = xr[t+256]; cls[t+512] = xr[t+512];
    __syncthreads();
    float v = 0.f;
    if (t < 192){
      const int j = t*2;
      float a0=0.f, a1=0.f, b0=0.f, b1=0.f;
      for (int i = 0; i < 768; i += 2){
        const float2 w0 = *(const float2*)(t_w1 + (u64)i*384 + j);
        const float2 w1v = *(const float2*)(t_w1 + (u64)(i+1)*384 + j);
        a0 = fmaf(cls[i],   w0.x,  a0);
        b0 = fmaf(cls[i],   w0.y,  b0);
        a1 = fmaf(cls[i+1], w1v.x, a1);
        b1 = fmaf(cls[i+1], w1v.y, b1);
      }
      const float2 bb = *(const float2*)(t_b1 + j);
      const float2 ww = *(const float2*)(t_w2 + j);
      const float hA = fmaxf(a0 + a1 + bb.x, 0.f);
      const float hB = fmaxf(b0 + b1 + bb.y, 0.f);
      v = hA*ww.x + hB*ww.y;
    }
    #pragma unroll
    for (int off = 1; off < 64; off <<= 1) v += __shfl_xor(v, off);
    if ((t & 63) == 0) part[t >> 6] = v;
    __syncthreads();
    if (t == 0){
      const float s2 = part[0] + part[1] + part[2] + part[3] + t_b2[0];
      const float sig  = 1.f / (1.f + expf(-s2));
      const float temp = 0.5f + 2.5f * sig;   // TEMP_MIN + (MAX-MIN)*sigmoid
      lsc[b] = 0.125f / temp;                 // D^-0.5 / temperature
    }
  }
}

// ---------- GEMM: A[M][768] x Bm[N][768]^T ----------
// OUTF=1 -> f32 out + bias; OUTF=2 -> bf16 out, cols<768 scaled by lsc[row/577]
// BK=64, LDS tiles [128][64] u16, 16B-unit XOR swizzle unit' = unit ^ (row&7),
// staged via global_load_lds (linear LDS dest) + pre-swizzled global source.
// 1D grid + bijective XCD chunk swizzle (T1): each XCD takes a contiguous
// block range -> A row-panels fetched once per XCD, B L2-resident.
template<int OUTF>
__global__ __launch_bounds__(256, 2) void gemm_nt(
    const u16* __restrict__ A, const u16* __restrict__ Bm,
    void* __restrict__ Cout, const float* __restrict__ bias,
    const float* __restrict__ lsc, int M, int N, int nbx){
  constexpr int K = 768;
  __shared__ u16 As[128*64];
  __shared__ u16 Bs[128*64];
  const int t = threadIdx.x, l = t & 63, w = t >> 6;
  // XCD swizzle (m204 bijective form)
  const u32 nwg = gridDim.x;
  const u32 qc = nwg >> 3, rc = nwg & 7;
  const u32 xcd = blockIdx.x & 7, lin = blockIdx.x >> 3;
  const u32 wg = (xcd < rc ? xcd*(qc+1) : rc*(qc+1) + (xcd-rc)*qc) + lin;
  const int bm = (int)(wg / (u32)nbx)*128, bn = (int)(wg % (u32)nbx)*128;
  const int wr = (w >> 1)*64, wc = (w & 1)*64;
  const int g = l >> 4, r16 = l & 15;

  f32x4 acc[4][4];
  #pragma unroll
  for (int i = 0; i < 4; i++)
    #pragma unroll
    for (int j = 0; j < 4; j++) acc[i][j] = (f32x4){0.f,0.f,0.f,0.f};

  const int srow = t >> 3;                  // 0..31
  const int su   = (t & 7) ^ (srow & 7);    // source 16B-unit within the 64-k slab
  const u16* gA[4]; const u16* gB[4];
  #pragma unroll
  for (int i = 0; i < 4; i++){
    int ra = bm + i*32 + srow; if (ra > M-1) ra = M-1;
    gA[i] = A  + (u64)ra*K + su*8;
    gB[i] = Bm + (u64)(bn + i*32 + srow)*K + su*8;
  }
  u16* lA = As + t*8;
  u16* lB = Bs + t*8;

  for (int kt = 0; kt < K; kt += 64){
    #pragma unroll
    for (int i = 0; i < 4; i++) gload16(gA[i] + kt, lA + i*2048);
    #pragma unroll
    for (int i = 0; i < 4; i++) gload16(gB[i] + kt, lB + i*2048);
    __syncthreads();
    #pragma unroll
    for (int s = 0; s < 2; s++){
      const int c   = s*4 + (g >> 1);
      const int off = (g & 1)*4;
      bf16x8 af[4], bfr[4];
      #pragma unroll
      for (int m = 0; m < 4; m++){
        const int R = wr + m*16 + r16;
        const int i1 = R*64 + ((c ^ (R & 7))*8) + off;
        af[m] = mkfrag(*(const uint2*)(As + i1), *(const uint2*)(As + (i1 ^ 16)));
      }
      #pragma unroll
      for (int n = 0; n < 4; n++){
        const int R = wc + n*16 + r16;
        const int i1 = R*64 + ((c ^ (R & 7))*8) + off;
        bfr[n] = mkfrag(*(const uint2*)(Bs + i1), *(const uint2*)(Bs + (i1 ^ 16)));
      }
      #pragma unroll
      for (int m = 0; m < 4; m++)
        #pragma unroll
        for (int n = 0; n < 4; n++)
          acc[m][n] = __builtin_amdgcn_mfma_f32_16x16x32_bf16(af[m], bfr[n], acc[m][n], 0, 0, 0);
    }
    __syncthreads();
  }
  const int row0 = bm + wr + g*4;
  const int col0 = bn + wc + r16;
  const bool isQ = (OUTF == 2) && (bn < 768);   // block-uniform
  #pragma unroll
  for (int m = 0; m < 4; m++){
    #pragma unroll
    for (int rr = 0; rr < 4; rr++){
      const int row = row0 + m*16 + rr;
      if (row < M){
        float qs = 1.0f;
        if (isQ) qs = lsc[row/577];
        #pragma unroll
        for (int n = 0; n < 4; n++){
          const int col = col0 + n*16;
          const float v = acc[m][n][rr];
          if (OUTF == 1) ((float*)Cout)[(u64)row*N + col] = v + bias[col];
          else           ((u16*)Cout)[(u64)row*N + col]  = f2bf(v*qs);
        }
      }
    }
  }
}

// ---------- flash attention ----------
// qkv: [9232][2304] bf16 (q|k|v each H*64), Q pre-scaled by D^-0.5/temp.
// Main loop: 9 full K-tiles of 64 (no masking); key 576 handled by an
// in-register tail (dot + rank-1 update). Double-buffered K/Vt LDS, async
// stage split, ONE barrier per iteration. Register-resident P via S^T trick.
// VALU diet: cvt_pk_bf16_f32 packed P (T12), defer-max rescale THR=8 (T13).
// Grid: 1D 1920 with XCD-chunk swizzle (T1).
__global__ __launch_bounds__(256, 2) void attn_kernel(
    const u16* __restrict__ qkv, u16* __restrict__ aout){
  const u32 lid  = blockIdx.x;
  const u32 orig = (lid & 7u)*240u + (lid >> 3);   // bijective: 1920 = 8*240
  const int qt = orig % 10u;
  const u32 bh = orig / 10u;
  const int h  = bh % 12u;
  const int b  = bh / 12u;
  const int t = threadIdx.x, w = t >> 6, l = t & 63;
  const int g = l >> 4, r16 = l & 15;
  __shared__ u16 Ks[2][64*64];   // [key][d], 16B-unit XOR swizzle key=(row&7)
  __shared__ u16 Vt[2][64*64];   // [d][key], swizzle key=((d^(d>>3))&7)
  const u16* base = qkv + (u64)b*577*2304 + (u64)h*64;

  int qn = qt*64 + w*16 + r16; if (qn > 576) qn = 576;
  bf16x8 qf[2];
  {
    const u16* qr = base + (u64)qn*2304;
    #pragma unroll
    for (int s = 0; s < 2; s++)
      qf[s] = mkfrag(*(const uint2*)(qr + s*32 + g*4),
                     *(const uint2*)(qr + s*32 + g*4 + 16));
  }
  float m_run = -1e30f, l_run = 0.f;
  f32x4 oacc[4];
  #pragma unroll
  for (int i = 0; i < 4; i++) oacc[i] = (f32x4){0,0,0,0};

  const int srcb = (l & 48) | (((l >> 4) & 3)*4);   // lane holding q-row 4g+rr at +rr

  // staging sources (point at NEXT tile to load)
  const int srow = t >> 3;                         // 0..31
  const int su   = (t & 7) ^ (srow & 7);           // pre-swizzled K source unit
  const u16* pK = base + 768  + (u64)srow*2304 + su*8;
  const int kr0 = (t >> 3)*2;                      // V: two consecutive key rows
  const u16* pV = base + 1536 + (u64)kr0*2304 + (t & 7)*8;
  // kt-invariant Vt scatter offsets (u16 units)
  u32 vtoff[8];
  #pragma unroll
  for (int j = 0; j < 8; j++){
    const int d = (t & 7)*8 + j;
    const int key = (d ^ (d >> 3)) & 7;
    vtoff[j] = d*64 + (((kr0 >> 3) ^ key)*8) + (kr0 & 7);
  }

  uint4 vr0, vr1;
  // ---- prologue: stage tile 0 ----
  gload16(pK,            &Ks[0][0] + t*8);
  gload16(pK + 32*2304,  &Ks[0][0] + t*8 + 2048);
  vr0 = *(const uint4*)pV;
  vr1 = *(const uint4*)(pV + 2304);
  pK += 64*2304; pV += 64*2304;
  {
    const u16* e0 = (const u16*)&vr0;
    const u16* e1 = (const u16*)&vr1;
    #pragma unroll
    for (int j = 0; j < 8; j++)
      *(u32*)(&Vt[0][0] + vtoff[j]) = (u32)e0[j] | ((u32)e1[j] << 16);
  }
  __syncthreads();

  for (int kt = 0; kt < 9; kt++){
    const int cur = kt & 1, nb = cur ^ 1;
    u16* ksc = &Ks[cur][0];
    u16* vtc = &Vt[cur][0];
    // issue next-tile loads (hidden under this tile's compute)
    if (kt < 8){
      gload16(pK,           &Ks[nb][0] + t*8);
      gload16(pK + 32*2304, &Ks[nb][0] + t*8 + 2048);
      vr0 = *(const uint4*)pV;
      vr1 = *(const uint4*)(pV + 2304);
      pK += 64*2304; pV += 64*2304;
    }

    // S^T = K Q^T  (lane holds keys fn*16+4g+rr for q-row r16)
    f32x4 sacc[4];
    #pragma unroll
    for (int i = 0; i < 4; i++) sacc[i] = (f32x4){0,0,0,0};
    #pragma unroll
    for (int fn = 0; fn < 4; fn++){
      const int kr = fn*16 + r16;
      const int kk = kr & 7;
      const u16* rowp = ksc + kr*64 + (g & 1)*4;
      #pragma unroll
      for (int s = 0; s < 2; s++){
        const int b0 = (4*s + (g >> 1)) ^ kk;
        sacc[fn] = __builtin_amdgcn_mfma_f32_16x16x32_bf16(
            mkfrag(*(const uint2*)(rowp + b0*8), *(const uint2*)(rowp + (b0 ^ 2)*8)),
            qf[s], sacc[fn], 0, 0, 0);
      }
    }
    // online softmax: all 16 values on a lane belong to q-row r16
    float mx = sacc[0][0];
    #pragma unroll
    for (int fn = 0; fn < 4; fn++)
      #pragma unroll
      for (int rr = 0; rr < 4; rr++) mx = fmaxf(mx, sacc[fn][rr]);
    mx = fmaxf(mx, __shfl_xor(mx, 16));
    mx = fmaxf(mx, __shfl_xor(mx, 32));
    // defer-max (T13): only rescale when the running max grew by > 8
    if (!__all(mx - m_run <= 8.f)){
      const float nm = fmaxf(m_run, mx);
      const float corr = __expf(m_run - nm);
      l_run *= corr;
      float corrO[4];
      #pragma unroll
      for (int rr = 0; rr < 4; rr++) corrO[rr] = __shfl(corr, srcb + rr);
      #pragma unroll
      for (int df = 0; df < 4; df++)
        #pragma unroll
        for (int rr = 0; rr < 4; rr++) oacc[df][rr] *= corrO[rr];
      m_run = nm;
    }
    float pf[4][4];
    float rs = 0.f;
    #pragma unroll
    for (int fn = 0; fn < 4; fn++)
      #pragma unroll
      for (int rr = 0; rr < 4; rr++){
        const float p = __expf(sacc[fn][rr] - m_run);   // bounded by e^8
        rs += p;
        pf[fn][rr] = p;
      }
    rs += __shfl_xor(rs, 16);
    rs += __shfl_xor(rs, 32);
    l_run += rs;
    // O += P V  (P packed in-register via v_cvt_pk_bf16_f32, T12)
    #pragma unroll
    for (int s = 0; s < 2; s++){
      union { bf16x8 v; u32 u[4]; } pa;
      asm("v_cvt_pk_bf16_f32 %0, %1, %2" : "=v"(pa.u[0]) : "v"(pf[2*s][0]),   "v"(pf[2*s][1]));
      asm("v_cvt_pk_bf16_f32 %0, %1, %2" : "=v"(pa.u[1]) : "v"(pf[2*s][2]),   "v"(pf[2*s][3]));
      asm("v_cvt_pk_bf16_f32 %0, %1, %2" : "=v"(pa.u[2]) : "v"(pf[2*s+1][0]), "v"(pf[2*s+1][1]));
      asm("v_cvt_pk_bf16_f32 %0, %1, %2" : "=v"(pa.u[3]) : "v"(pf[2*s+1][2]), "v"(pf[2*s+1][3]));
      #pragma unroll
      for (int df = 0; df < 4; df++){
        const int vd = df*16 + r16;
        const int vk = (vd ^ (vd >> 3)) & 7;
        const u16* vrp = vtc + vd*64 + (g & 1)*4;
        const int c0 = (4*s + (g >> 1)) ^ vk;
        const bf16x8 vf = mkfrag(*(const uint2*)(vrp + c0*8),
                                 *(const uint2*)(vrp + (c0 ^ 2)*8));
        oacc[df] = __builtin_amdgcn_mfma_f32_16x16x32_bf16(pa.v, vf, oacc[df], 0, 0, 0);
      }
    }
    // commit next V tile to LDS, then barrier (drains gload_lds too)
    if (kt < 8){
      const u16* e0 = (const u16*)&vr0;
      const u16* e1 = (const u16*)&vr1;
      u16* vtn = &Vt[nb][0];
      #pragma unroll
      for (int j = 0; j < 8; j++)
        *(u32*)(vtn + vtoff[j]) = (u32)e0[j] | ((u32)e1[j] << 16);
      __syncthreads();
    }
  }

  // ---- tail: key 576 (in-register dot + rank-1 update) ----
  {
    const u16* kr576 = base + 768 + (u64)576*2304;
    float s576 = 0.f;
    #pragma unroll
    for (int s = 0; s < 2; s++){
      const uint2 k0 = *(const uint2*)(kr576 + s*32 + g*4);
      const uint2 k1 = *(const uint2*)(kr576 + s*32 + g*4 + 16);
      union { bf16x8 v; u32 u[4]; } qq; qq.v = qf[s];
      const u32 ku[4] = {k0.x, k0.y, k1.x, k1.y};
      #pragma unroll
      for (int j = 0; j < 4; j++){
        const float ql = __builtin_bit_cast(float, qq.u[j] << 16);
        const float qh = __builtin_bit_cast(float, qq.u[j] & 0xffff0000u);
        const float kl = __builtin_bit_cast(float, ku[j] << 16);
        const float kh = __builtin_bit_cast(float, ku[j] & 0xffff0000u);
        s576 = fmaf(ql, kl, s576);
        s576 = fmaf(qh, kh, s576);
      }
    }
    s576 += __shfl_xor(s576, 16);
    s576 += __shfl_xor(s576, 32);
    if (!__all(s576 - m_run <= 8.f)){
      const float nm = fmaxf(m_run, s576);
      const float corr = __expf(m_run - nm);
      l_run *= corr;
      float corrO[4];
      #pragma unroll
      for (int rr = 0; rr < 4; rr++) corrO[rr] = __shfl(corr, srcb + rr);
      #pragma unroll
      for (int df = 0; df < 4; df++)
        #pragma unroll
        for (int rr = 0; rr < 4; rr++) oacc[df][rr] *= corrO[rr];
      m_run = nm;
    }
    const float p576 = __expf(s576 - m_run);
    l_run += p576;
    float pbr[4];
    #pragma unroll
    for (int rr = 0; rr < 4; rr++) pbr[rr] = __shfl(p576, srcb + rr);
    const u16* v576 = base + 1536 + (u64)576*2304;
    #pragma unroll
    for (int df = 0; df < 4; df++){
      const float vv = __builtin_bit_cast(float, (u32)v576[df*16 + r16] << 16);
      #pragma unroll
      for (int rr = 0; rr < 4; rr++)
        oacc[df][rr] = fmaf(pbr[rr], vv, oacc[df][rr]);
    }
  }

  // epilogue: O/l -> bf16 [row][h*64+d]
  float lO[4];
  #pragma unroll
  for (int rr = 0; rr < 4; rr++) lO[rr] = __shfl(l_run, srcb + rr);
  #pragma unroll
  for (int df = 0; df < 4; df++){
    const int d = df*16 + r16;
    #pragma unroll
    for (int rr = 0; rr < 4; rr++){
      const int n = qt*64 + w*16 + g*4 + rr;
      if (n <= 576){
        const float v = oacc[df][rr] / lO[rr];
        aout[(u64)(b*577 + n)*768 + h*64 + d] = f2bf(v);
      }
    }
  }
}

// ---------- launcher ----------
extern "C" void kernel_launch(void* const* d_in, const int* in_sizes, int n_in,
                              void* d_out, int out_size, void* d_ws, size_t ws_size,
                              hipStream_t stream){
  const float* x      = (const float*)d_in[0];
  const float* qkv_w  = (const float*)d_in[1];
  const float* proj_w = (const float*)d_in[2];
  const float* proj_b = (const float*)d_in[3];
  const float* t_w1   = (const float*)d_in[4];
  const float* t_b1   = (const float*)d_in[5];
  const float* t_w2   = (const float*)d_in[6];
  const float* t_b2   = (const float*)d_in[7];

  // ws layout (256B-aligned). ao reuses xb's region (xb dead after qkv GEMM).
  const u64 off_xb  = 256;                    // x bf16 [9232][768]  / later: attn out
  const u64 off_qwT = off_xb  + 14180352ull;  // qkv_w^T [2304][768]
  const u64 off_pwT = off_qwT + 3538944ull;   // proj_w^T [768][768]
  const u64 off_qkv = off_pwT + 1179648ull;   // qkv bf16 [9232][2304]
  const u64 need    = off_qkv + 42541056ull;
  if (ws_size < need) return;  // visible-failure guard: output stays poisoned

  char* ws  = (char*)d_ws;
  float* lsc = (float*)ws;
  u16* xb   = (u16*)(ws + off_xb);
  u16* qwT  = (u16*)(ws + off_qwT);
  u16* pwT  = (u16*)(ws + off_pwT);
  u16* qkv  = (u16*)(ws + off_qkv);
  u16* ao   = xb;   // reuse

  prep_kernel<<<3344, 256, 0, stream>>>(x, qkv_w, proj_w, t_w1, t_b1, t_w2, t_b2,
                                        xb, qwT, pwT, lsc);
  gemm_nt<2><<<1314, 256, 0, stream>>>(xb, qwT, qkv, nullptr, lsc, 9232, 2304, 18);
  attn_kernel<<<1920, 256, 0, stream>>>(qkv, ao);
  gemm_nt<1><<<438, 256, 0, stream>>>(ao, pwT, d_out, proj_b, nullptr, 9232, 768, 6);
}